// Round 8
// baseline (648.800 us; speedup 1.0000x reference)
//
#include <hip/hip_runtime.h>
#include <cstdint>

#define BATCH 8
#define NPTS  4096
#define MPTS  1024
#define DIM   64

typedef float v2f __attribute__((ext_vector_type(2)));
typedef unsigned long long u64;
typedef unsigned int u32;

// True VOP3P packed fp32 (2 lanes per instruction) — guarantees half the
// issue count vs scalar lowering. IEEE RN per element, identical rounding to
// scalar ops, and asm blocks are opaque to contraction.
__device__ __forceinline__ v2f pk_add(v2f a, v2f b) {
  v2f d; asm("v_pk_add_f32 %0, %1, %2" : "=v"(d) : "v"(a), "v"(b)); return d;
}
__device__ __forceinline__ v2f pk_mul(v2f a, v2f b) {
  v2f d; asm("v_pk_mul_f32 %0, %1, %2" : "=v"(d) : "v"(a), "v"(b)); return d;
}

// f64-ordered keys: (f32 dist bits << 32) | aux as a positive finite double;
// value order == u64 bit order, so v_max_f64/v_min_f64 give exact u64
// max/min in one instruction (see round-3 notes).
__device__ __forceinline__ double mk_key_bits(int dist_bits, int lo) {
  return __hiloint2double(dist_bits, lo);
}
__device__ __forceinline__ u32 key_lo(double d) { return (u32)__double2loint(d); }

// One DPP step of a 64-lane f64-key max reduction. bound_ctrl=true -> invalid
// source lanes read 0.0, the identity for max of positive keys.
#define WAVE_MAX_F64_STEP(x, ctrl)                                                   \
  {                                                                                  \
    const int lo_ = __builtin_amdgcn_update_dpp(0, __double2loint(x), (ctrl), 0xf, 0xf, true); \
    const int hi_ = __builtin_amdgcn_update_dpp(0, __double2hiint(x), (ctrl), 0xf, 0xf, true); \
    const double y_ = __hiloint2double(hi_, lo_);                                    \
    (x) = fmax((x), y_);                                                             \
  }

// -------------------- Kernel 1: farthest point sampling --------------------
// r3 structure (best so far): one cloud/block, 256 threads, 16 pts/thread,
// one barrier/iter. Round-8 slimming: (1) dist math in explicit v_pk_* asm
// (8 insts / 2 points); (2) mind state lives INSIDE the f64 key (hi=mind
// bits, lo=~idx const) — update is a single v_min_f64 against (d, state.lo),
// no separate min, no aux registers. Argmax key (mind,~idx) -> fmax = largest
// dist, tie -> smallest idx (np.argmax). 6-step DPP wave reduce, lane-63 slot
// write, barrier, 4-slot combine, winner coords via broadcast ds_read_b128.
__global__ __launch_bounds__(256) void fps_kernel(const float* __restrict__ pos,
                                                  int* __restrict__ gidx) {
#pragma clang fp contract(off)
  const int b = blockIdx.x;
  const int t = threadIdx.x;
  const float* p = pos + (size_t)b * NPTS * 3;

  __shared__ float4 sp[NPTS];
  __shared__ double red[2][4];

  v2f px[8], py[8], pz[8];
  double state[16];  // (mind_bits << 32) | ~local_idx, per owned point
#pragma unroll
  for (int k = 0; k < 16; ++k) {
    const int i = t + k * 256;
    const float a = p[3 * i + 0];
    const float c = p[3 * i + 1];
    const float d = p[3 * i + 2];
    sp[i] = make_float4(a, c, d, 0.0f);
    px[k >> 1][k & 1] = a;
    py[k >> 1][k & 1] = c;
    pz[k >> 1][k & 1] = d;
    state[k] = mk_key_bits(0x7F7FFFFF, (int)~(u32)i);  // mind = FLT_MAX
  }
  __syncthreads();

  if (t == 0) gidx[b * MPTS] = b * NPTS;  // deterministic start at local idx 0
  float4 w = sp[0];
  float lx = w.x, ly = w.y, lz = w.z;

  for (int it = 1; it < MPTS; ++it) {
    // negated query splat: pk_add(p, -q) == p - q bit-exactly
    const v2f vnx = {-lx, -lx}, vny = {-ly, -ly}, vnz = {-lz, -lz};
#pragma unroll
    for (int g = 0; g < 8; ++g) {
      // strict fp32 order: ((dx*dx + dy*dy) + dz*dz), 2 points per inst
      const v2f dx = pk_add(px[g], vnx);
      const v2f dy = pk_add(py[g], vny);
      const v2f dz = pk_add(pz[g], vnz);
      const v2f xx = pk_mul(dx, dx);
      const v2f yy = pk_mul(dy, dy);
      const v2f zz = pk_mul(dz, dz);
      const v2f s  = pk_add(xx, yy);
      const v2f d  = pk_add(s, zz);
      // mind update fused into the key: one v_min_f64 per point
      const double c0 = mk_key_bits(__float_as_int(d[0]), __double2loint(state[2 * g]));
      const double c1 = mk_key_bits(__float_as_int(d[1]), __double2loint(state[2 * g + 1]));
      state[2 * g]     = fmin(state[2 * g], c0);
      state[2 * g + 1] = fmin(state[2 * g + 1], c1);
    }
    // thread-local argmax tree over the 16 key-states (15 v_max_f64)
    double m0 = fmax(state[0], state[1]);
    double m1 = fmax(state[2], state[3]);
    double m2 = fmax(state[4], state[5]);
    double m3 = fmax(state[6], state[7]);
    double m4 = fmax(state[8], state[9]);
    double m5 = fmax(state[10], state[11]);
    double m6 = fmax(state[12], state[13]);
    double m7 = fmax(state[14], state[15]);
    double best = fmax(fmax(fmax(m0, m1), fmax(m2, m3)),
                       fmax(fmax(m4, m5), fmax(m6, m7)));

    // 64-lane wave max via DPP; lane 63 holds the wave result.
    WAVE_MAX_F64_STEP(best, 0x111);  // row_shr:1
    WAVE_MAX_F64_STEP(best, 0x112);  // row_shr:2
    WAVE_MAX_F64_STEP(best, 0x114);  // row_shr:4
    WAVE_MAX_F64_STEP(best, 0x118);  // row_shr:8
    WAVE_MAX_F64_STEP(best, 0x142);  // row_bcast:15
    WAVE_MAX_F64_STEP(best, 0x143);  // row_bcast:31

    const int buf = it & 1;  // double-buffered slots: 1 barrier/iter
    if ((t & 63) == 63) red[buf][t >> 6] = best;
    __syncthreads();

    const double c = fmax(fmax(red[buf][0], red[buf][1]),
                          fmax(red[buf][2], red[buf][3]));
    const u32 widx = ~key_lo(c);  // low word = ~idx

    w = sp[widx];  // broadcast ds_read_b128 (same address all lanes)
    lx = w.x; ly = w.y; lz = w.z;
    if (t == 0) gidx[b * MPTS + it] = b * NPTS + (int)widx;
  }
}

// -------------- Kernel 2: k=1 NN + output assembly (fused) -----------------
// B*32 blocks x 256 threads. Phase 1: 128 hr points/block, 2 threads per
// point splitting M=1024 lr points in half; 4-pt groups via ds_read_b128 +
// pk math. Argmin key (dist_bits<<32)|j -> v_min_f64 = smallest dist, tie ->
// smallest j (np.argmin). Phase 2: wave-per-row assembly (256B coalesced
// chunks) + zeros + batch outputs.
__global__ __launch_bounds__(256) void nn_assemble_kernel(
    const float* __restrict__ x, const float* __restrict__ pos,
    const int* __restrict__ gidx, float* __restrict__ out) {
#pragma clang fp contract(off)
  const int b = blockIdx.x >> 5;
  const int chunk = blockIdx.x & 31;
  const int t = threadIdx.x;

  __shared__ __align__(16) float lrx[MPTS], lry[MPTS], lrz[MPTS];
  __shared__ int snng[128];
  for (int j = t; j < MPTS; j += 256) {
    const int g = gidx[b * MPTS + j];
    lrx[j] = pos[3 * g + 0];
    lry[j] = pos[3 * g + 1];
    lrz[j] = pos[3 * g + 2];
  }
  __syncthreads();

  {
    const int pt = chunk * 128 + (t >> 1);
    const int half = t & 1;
    const int i = b * NPTS + pt;  // global hr point index
    const float qx = pos[3 * i + 0];
    const float qy = pos[3 * i + 1];
    const float qz = pos[3 * i + 2];
    const v2f vnx = {-qx, -qx}, vny = {-qy, -qy}, vnz = {-qz, -qz};

    double best = __hiloint2double(0x7FEFFFFF, 0xFFFFFFFF);  // > all keys
    const int j0 = half * 512;
#pragma unroll 4
    for (int s = 0; s < 128; ++s) {
      const int j = j0 + 4 * s;
      const float4 qxv = *(const float4*)&lrx[j];  // ds_read_b128
      const float4 qyv = *(const float4*)&lry[j];
      const float4 qzv = *(const float4*)&lrz[j];
      const v2f x01 = {qxv.x, qxv.y}, x23 = {qxv.z, qxv.w};
      const v2f y01 = {qyv.x, qyv.y}, y23 = {qyv.z, qyv.w};
      const v2f z01 = {qzv.x, qzv.y}, z23 = {qzv.z, qzv.w};
      const v2f dx0 = pk_add(x01, vnx), dx1 = pk_add(x23, vnx);
      const v2f dy0 = pk_add(y01, vny), dy1 = pk_add(y23, vny);
      const v2f dz0 = pk_add(z01, vnz), dz1 = pk_add(z23, vnz);
      const v2f d0 = pk_add(pk_add(pk_mul(dx0, dx0), pk_mul(dy0, dy0)), pk_mul(dz0, dz0));
      const v2f d1 = pk_add(pk_add(pk_mul(dx1, dx1), pk_mul(dy1, dy1)), pk_mul(dz1, dz1));
      const double c0 = mk_key_bits(__float_as_int(d0[0]), j + 0);
      const double c1 = mk_key_bits(__float_as_int(d0[1]), j + 1);
      const double c2 = mk_key_bits(__float_as_int(d1[0]), j + 2);
      const double c3 = mk_key_bits(__float_as_int(d1[1]), j + 3);
      best = fmin(best, fmin(fmin(c0, c1), fmin(c2, c3)));
    }
    // pair combine across the two halves (lanes differ only in bit 0)
    const int blo = __shfl_xor(__double2loint(best), 1, 64);
    const int bhi = __shfl_xor(__double2hiint(best), 1, 64);
    best = fmin(best, __hiloint2double(bhi, blo));
    if (half == 0) snng[t >> 1] = gidx[b * MPTS + (int)key_lo(best)];
  }
  __syncthreads();

  // Phase 2: rows. Row = [x(64) | pos(3) | x[g](64) | pos[g](3)].
  const int wave = t >> 6, lane = t & 63;
  float* o2 = out + (size_t)BATCH * NPTS * 134;  // zeros output [B*N,3]
  float* o3 = o2 + (size_t)BATCH * NPTS * 3;     // batch output [B*N]
#pragma unroll
  for (int r = wave; r < 128; r += 4) {
    const int i = b * NPTS + chunk * 128 + r;
    const int g = snng[r];
    float* o = out + (size_t)i * 134;
    o[lane] = x[(size_t)i * DIM + lane];
    o[67 + lane] = x[(size_t)g * DIM + lane];
    if (lane < 3) {
      o[64 + lane] = pos[3 * i + lane];
      o[131 + lane] = pos[3 * g + lane];
      o2[3 * i + lane] = 0.0f;
    }
    if (lane == 0) o3[i] = (float)b;
  }
}

// ---------------------------------------------------------------------------
extern "C" void kernel_launch(void* const* d_in, const int* in_sizes, int n_in,
                              void* d_out, int out_size, void* d_ws, size_t ws_size,
                              hipStream_t stream) {
  const float* x = (const float*)d_in[0];
  const float* pos = (const float*)d_in[1];

  int* gidx = (int*)d_ws;  // [B*M] global indices of sampled points
  float* out = (float*)d_out;

  fps_kernel<<<BATCH, 256, 0, stream>>>(pos, gidx);
  nn_assemble_kernel<<<BATCH * 32, 256, 0, stream>>>(x, pos, gidx, out);
}